// Round 17
// baseline (198.137 us; speedup 1.0000x reference)
//
#include <hip/hip_runtime.h>
#include <math.h>

#define L 8
#define FP8_SCALE 512.0f
#define FP8_INV   0.001953125f   // 1/512

typedef unsigned int  u32;
typedef unsigned short u16;
typedef __attribute__((ext_vector_type(8))) short bf16x8;
typedef __attribute__((ext_vector_type(4))) float f32x4;
typedef __attribute__((ext_vector_type(2))) float f32x2;

// fp32 -> bf16 round-to-nearest-even
__device__ inline u16 f2bf(float x) {
    u32 u = __float_as_uint(x);
    return (u16)((u + 0x7fffu + ((u >> 16) & 1u)) >> 16);
}
// unpack 2 packed bf16 (low = even elem, high = odd elem)
__device__ inline float2 bf2f2(u32 v) {
    float2 r;
    r.x = __uint_as_float(v << 16);
    r.y = __uint_as_float(v & 0xffff0000u);
    return r;
}
__device__ inline float gelu_t(float x) {
    return 0.5f * x * (1.0f + tanhf(0.7978845608028654f *
           (x + 0.044715f * x * x * x)));
}

// ---------------------------------------------------------------------------
// Device bodies
// ---------------------------------------------------------------------------
__device__ inline void zero_body(int bid, int tid, int* __restrict__ deg, int Na)
{
    int i = bid * 256 + tid;
    if (i < Na) deg[i] = 0;
}

__device__ inline void conv_emb_body(int bid, int tid,
    const float* __restrict__ emb, u32* __restrict__ emb_bf, int n2)
{
    int i = bid * 256 + tid;
    if (i >= n2) return;
    float2 e = *(const float2*)(emb + (size_t)i * 2);
    emb_bf[i] = ((u32)f2bf(e.y) << 16) | (u32)f2bf(e.x);
}

// ILP-8 degree histogram WITH rank capture: rank[e] = old count of dst bucket.
__device__ inline void hist_body8(int bid, int tid,
    const int* __restrict__ dstI, int* __restrict__ deg,
    int* __restrict__ rank, int E, int stride)
{
    int e0 = bid * 256 + tid;
    int d[8], r[8];
#pragma unroll
    for (int j = 0; j < 8; ++j) {
        int e = e0 + j * stride;
        d[j] = (e < E) ? dstI[e] : -1;
    }
#pragma unroll
    for (int j = 0; j < 8; ++j)
        r[j] = (d[j] >= 0) ? atomicAdd(&deg[d[j]], 1) : 0;
#pragma unroll
    for (int j = 0; j < 8; ++j) {
        int e = e0 + j * stride;
        if (d[j] >= 0) rank[e] = r[j];
    }
}

__device__ inline void fold_body(int bid, int tid,
    const float* __restrict__ Wk1, const float* __restrict__ Wq0,
    const float* __restrict__ Wv1, const float* __restrict__ Watt1,
    const float* __restrict__ Wmsg1, const float* __restrict__ Wout0,
    const float* __restrict__ lin_w,
    u16* __restrict__ wkaT, u16* __restrict__ wvmT,
    u16* __restrict__ wqT, u16* __restrict__ w1T, u16* __restrict__ lwT)
{
    int id = bid * 256 + tid;   // < 5*16384
    int which = id >> 14;
    int idx = id & 16383;
    int col = idx & 127;
    int k = idx >> 7;
    if (which == 0) {
        int h = col >> 5, f = col & 31;
        float s = 0.f;
        for (int d = 0; d < 32; ++d)
            s += Wk1[k * 128 + h * 32 + d] * Watt1[h * 1024 + d * 32 + f];
        wkaT[col * 128 + k] = f2bf(s);
    } else if (which == 1) {
        int h = col >> 5, f = col & 31;
        float s = 0.f;
        for (int d = 0; d < 32; ++d)
            s += Wv1[k * 128 + h * 32 + d] * Wmsg1[h * 1024 + d * 32 + f];
        wvmT[col * 128 + k] = f2bf(s);
    } else if (which == 2) {
        wqT[col * 128 + k] = f2bf(Wq0[k * 128 + col]);
    } else if (which == 3) {
        float s = 0.f;
        for (int d = 0; d < 128; ++d)
            s += Wout0[k * 128 + d] * lin_w[d * 128 + col];
        w1T[col * 128 + k] = f2bf(s);
    } else {
        lwT[col * 128 + k] = f2bf(lin_w[k * 128 + col]);
    }
}

// node encode: 16 threads/node, uint4 (8 dims, 16B) per lane, int4 token loads.
__device__ inline void encode_body(int bid, int tid,
    const int* __restrict__ tok_a, const int* __restrict__ tok_p,
    const uint4* __restrict__ emb_bf4,
    uint4* __restrict__ xa4, uint4* __restrict__ xp4, int Na, int Ntot)
{
    int i = bid * 256 + tid;
    int n = i >> 4, q = i & 15;
    if (n >= Ntot) return;
    const int* tok = (n < Na) ? (tok_a + (size_t)n * L)
                              : (tok_p + (size_t)(n - Na) * L);
    int4 t0 = *(const int4*)tok;
    int4 t1 = *(const int4*)(tok + 4);
    int tt[8] = {t0.x, t0.y, t0.z, t0.w, t1.x, t1.y, t1.z, t1.w};
    float a[8] = {0.f, 0.f, 0.f, 0.f, 0.f, 0.f, 0.f, 0.f};
    int cnt = 0;
#pragma unroll
    for (int l = 0; l < L; ++l) {
        int t = tt[l];
        if (t != 0) {
            cnt++;
            uint4 e = emb_bf4[(size_t)t * 16 + q];
            float2 e0 = bf2f2(e.x), e1 = bf2f2(e.y);
            float2 e2 = bf2f2(e.z), e3 = bf2f2(e.w);
            a[0] += e0.x; a[1] += e0.y; a[2] += e1.x; a[3] += e1.y;
            a[4] += e2.x; a[5] += e2.y; a[6] += e3.x; a[7] += e3.y;
        }
    }
    float dn = 1.0f / fmaxf((float)cnt, 1.0f);
#pragma unroll
    for (int j = 0; j < 8; ++j) a[j] = fmaxf(a[j] * dn, 0.f);
    uint4 o;
    o.x = ((u32)f2bf(a[1]) << 16) | (u32)f2bf(a[0]);
    o.y = ((u32)f2bf(a[3]) << 16) | (u32)f2bf(a[2]);
    o.z = ((u32)f2bf(a[5]) << 16) | (u32)f2bf(a[4]);
    o.w = ((u32)f2bf(a[7]) << 16) | (u32)f2bf(a[6]);
    if (n < Na) xa4[(size_t)n * 16 + q] = o;
    else        xp4[(size_t)(n - Na) * 16 + q] = o;
}

// ILP-8 rank-based scatter: NO atomics. csrc[rowptr[dst]+rank] = src.
__device__ inline void scatter_body8(int bid, int tid,
    const int* __restrict__ srcI, const int* __restrict__ dstI,
    const int* __restrict__ rank, const int* __restrict__ rowptr,
    int* __restrict__ csrc, int E, int stride)
{
    int e0 = bid * 256 + tid;
    int d[8], s[8], r[8];
#pragma unroll
    for (int j = 0; j < 8; ++j) {
        int e = e0 + j * stride;
        d[j] = (e < E) ? dstI[e] : -1;
        s[j] = (e < E) ? srcI[e] : 0;
        r[j] = (e < E) ? rank[e] : 0;
    }
    int base[8];
#pragma unroll
    for (int j = 0; j < 8; ++j)
        base[j] = (d[j] >= 0) ? rowptr[d[j]] : 0;
#pragma unroll
    for (int j = 0; j < 8; ++j)
        if (d[j] >= 0) csrc[base[j] + r[j]] = s[j];
}

// ---------------------------------------------------------------------------
// Packed kernels
// ---------------------------------------------------------------------------
// P0: zero deg | emb fp32 -> bf16
__global__ __launch_bounds__(256) void k_zero_conv(
    int* deg, int Na, int Bzero,
    const float* emb, u32* emb_bf, int n2)
{
    int b = blockIdx.x, t = threadIdx.x;
    if (b < Bzero) zero_body(b, t, deg, Na);
    else           conv_emb_body(b - Bzero, t, emb, emb_bf, n2);
}

// P1: hist (ILP8 + rank) | weight fold | node ENCODE (the long pole).
__global__ __launch_bounds__(256) void k_prep(
    const int* dstI, int* deg, int* rank, int E, int Bhist8, int stride,
    const float* Wk1, const float* Wq0, const float* Wv1,
    const float* Watt1, const float* Wmsg1, const float* Wout0,
    const float* lin_w, u16* wkaT, u16* wvmT, u16* wqT, u16* w1T, u16* lwT,
    int Bfold,
    const int* tok_a, const int* tok_p, const uint4* emb_bf4,
    uint4* xa4, uint4* xp4, int Na, int Ntot)
{
    int b = blockIdx.x, t = threadIdx.x;
    if (b < Bhist8)               hist_body8(b, t, dstI, deg, rank, E, stride);
    else if (b < Bhist8 + Bfold)  fold_body(b - Bhist8, t, Wk1, Wq0, Wv1,
                                      Watt1, Wmsg1, Wout0, lin_w,
                                      wkaT, wvmT, wqT, w1T, lwT);
    else encode_body(b - Bhist8 - Bfold, t, tok_a, tok_p, emb_bf4,
                     xa4, xp4, Na, Ntot);
}

// P2: per-block scan over 1024 degrees -> local prefixes + block total
__global__ __launch_bounds__(256) void k_scan(
    const int* __restrict__ deg, int* __restrict__ locpref,
    int* __restrict__ blocksum, int Na)
{
    __shared__ int lds[256];
    int tid = threadIdx.x;
    int base = blockIdx.x * 1024 + tid * 4;
    int4 v = {0, 0, 0, 0};
    if (base + 3 < Na) {
        v = *(const int4*)(deg + base);
    } else {
        if (base + 0 < Na) v.x = deg[base + 0];
        if (base + 1 < Na) v.y = deg[base + 1];
        if (base + 2 < Na) v.z = deg[base + 2];
        if (base + 3 < Na) v.w = deg[base + 3];
    }
    int tot = v.x + v.y + v.z + v.w;
    lds[tid] = tot;
    __syncthreads();
    for (int off = 1; off < 256; off <<= 1) {
        int u = (tid >= off) ? lds[tid - off] : 0;
        __syncthreads();
        lds[tid] += u;
        __syncthreads();
    }
    int excl = lds[tid] - tot;
    if (base < Na) {
        int4 o;
        o.x = excl;
        o.y = excl + v.x;
        o.z = o.y + v.y;
        o.w = o.z + v.z;
        if (base + 3 < Na) *(int4*)(locpref + base) = o;
        else {
            locpref[base] = o.x;
            if (base + 1 < Na) locpref[base + 1] = o.y;
            if (base + 2 < Na) locpref[base + 2] = o.z;
        }
    }
    if (tid == 255) blocksum[blockIdx.x] = lds[255];
}

// P3: rowptr finalize — every block redundantly scans the <=256 block sums.
__global__ __launch_bounds__(256) void k_final(
    const int* __restrict__ locpref, const int* __restrict__ blocksum,
    int* __restrict__ rowptr, int nb, int Na)
{
    __shared__ int lds[256];
    __shared__ int excl[256];
    int t = threadIdx.x;
    int s = (t < nb) ? blocksum[t] : 0;
    lds[t] = s;
    __syncthreads();
    for (int off = 1; off < 256; off <<= 1) {
        int u = (t >= off) ? lds[t - off] : 0;
        __syncthreads();
        lds[t] += u;
        __syncthreads();
    }
    excl[t] = lds[t] - s;
    __syncthreads();
    int i = blockIdx.x * 256 + t;
    if (i < Na)
        rowptr[i] = locpref[i] + excl[i >> 10];
    if (blockIdx.x == 0 && t == 0)
        rowptr[Na] = lds[nb - 1];
}

// ---------------------------------------------------------------------------
// P4: rank-scatter (ILP8) | MFMA projection — round-robin interleaved.
// proj role 0 [0,gba):       qa = xa @ wqT (bf16 out)
// proj role 1 [gba,gba+gbp): kacc/macc in regs -> packed fp8 km8 direct
// Epilogues stage each wave's 16-row tile in a PRIVATE LDS slice (no barrier)
// then write 4 consecutive rows (1 KB) per uint4 instruction — full-line
// coalesced stores (fixes the 2x write amplification seen in round 16).
// ---------------------------------------------------------------------------
__global__ __launch_bounds__(256) void k_scat_proj(
    const int* srcI, const int* dstI, const int* rank, const int* rowptr,
    int* csrc, int E, int Bscat8, int stride,
    const u16* __restrict__ xa, const u16* __restrict__ xp,
    const u16* __restrict__ wqT, const u16* __restrict__ wkaT,
    const u16* __restrict__ wvmT,
    u16* __restrict__ qa, u32* __restrict__ km8, int Na, int Np, int gba,
    int Bproj)
{
    __shared__ u32 tile[4][16][64];   // 16 KB: per-wave 16x256B staging
    int b = blockIdx.x, t = threadIdx.x;
    if (b % 3 == 0) {
        int sb = b / 3;
        if (sb < Bscat8)
            scatter_body8(sb, t, srcI, dstI, rank, rowptr, csrc, E, stride);
        return;
    }
    int pb = (b / 3) * 2 + (b % 3 - 1);
    if (pb >= Bproj) return;

    int wave = t >> 6;
    int l = t & 63;
    int x = l & 15;
    int kb = (l >> 4) * 8;

    if (pb < gba) {
        // ---- author: qa = xa @ wqT ----
        int rbase = pb * 64 + wave * 16;
        int arow = rbase + x;
        if (arow >= Na) arow = Na - 1;
        bf16x8 af[4];
#pragma unroll
        for (int ks = 0; ks < 4; ++ks)
            af[ks] = *(const bf16x8*)(xa + (size_t)arow * 128 + ks * 32 + kb);
        f32x4 acc[8];
#pragma unroll
        for (int ct = 0; ct < 8; ++ct) acc[ct] = (f32x4){0.f, 0.f, 0.f, 0.f};
#pragma unroll
        for (int ks = 0; ks < 4; ++ks)
#pragma unroll
            for (int ct = 0; ct < 8; ++ct) {
                bf16x8 bf = *(const bf16x8*)(wqT + (size_t)(ct * 16 + x) * 128 + ks * 32 + kb);
                acc[ct] = __builtin_amdgcn_mfma_f32_16x16x32_bf16(af[ks], bf, acc[ct], 0, 0, 0);
            }
        // stage bf16 pairs into private LDS slice
#pragma unroll
        for (int ct = 0; ct < 8; ++ct) {
#pragma unroll
            for (int r = 0; r < 4; ++r) {
                float v0 = acc[ct][r];
                float v1 = __shfl_xor(v0, 1);
                if (!(x & 1)) {
                    int rr = ((l >> 4) << 2) + r;
                    tile[wave][rr][ct * 8 + (x >> 1)] =
                        ((u32)f2bf(v1) << 16) | (u32)f2bf(v0);
                }
            }
        }
        // coalesced write-out: 4 consecutive rows (1 KB) per iteration
#pragma unroll
        for (int it = 0; it < 4; ++it) {
            int rr = (l >> 4) + it * 4;
            int row = rbase + rr;
            if (row < Na) {
                uint4 v = *(const uint4*)&tile[wave][rr][(l & 15) * 4];
                *(uint4*)(qa + (size_t)row * 128 + (l & 15) * 8) = v;
            }
        }
    } else {
        // ---- paper: kacc/macc -> fp8 km8 (staged, coalesced) ----
        int b2 = pb - gba;
        int rbase = b2 * 64 + wave * 16;
        int arow = rbase + x;
        if (arow >= Np) arow = Np - 1;
        bf16x8 af[4];
#pragma unroll
        for (int ks = 0; ks < 4; ++ks)
            af[ks] = *(const bf16x8*)(xp + (size_t)arow * 128 + ks * 32 + kb);
        f32x4 kacc[8], macc[8];
#pragma unroll
        for (int ct = 0; ct < 8; ++ct) {
            kacc[ct] = (f32x4){0.f, 0.f, 0.f, 0.f};
            macc[ct] = (f32x4){0.f, 0.f, 0.f, 0.f};
        }
#pragma unroll
        for (int ks = 0; ks < 4; ++ks)
#pragma unroll
            for (int ct = 0; ct < 8; ++ct) {
                bf16x8 bk = *(const bf16x8*)(wkaT + (size_t)(ct * 16 + x) * 128 + ks * 32 + kb);
                kacc[ct] = __builtin_amdgcn_mfma_f32_16x16x32_bf16(af[ks], bk, kacc[ct], 0, 0, 0);
            }
#pragma unroll
        for (int ks = 0; ks < 4; ++ks)
#pragma unroll
            for (int ct = 0; ct < 8; ++ct) {
                bf16x8 bm = *(const bf16x8*)(wvmT + (size_t)(ct * 16 + x) * 128 + ks * 32 + kb);
                macc[ct] = __builtin_amdgcn_mfma_f32_16x16x32_bf16(af[ks], bm, macc[ct], 0, 0, 0);
            }
#pragma unroll
        for (int ct = 0; ct < 8; ++ct) {
#pragma unroll
            for (int r = 0; r < 4; ++r) {
                float k0 = kacc[ct][r] * FP8_SCALE;
                float k1 = __shfl_xor(k0, 1);
                float m0 = macc[ct][r] * FP8_SCALE;
                float m1 = __shfl_xor(m0, 1);
                if (!(x & 1)) {
                    int rr = ((l >> 4) << 2) + r;
                    int pk = __builtin_amdgcn_cvt_pk_fp8_f32(k0, k1, 0, false);
                    pk = __builtin_amdgcn_cvt_pk_fp8_f32(m0, m1, pk, true);
                    tile[wave][rr][ct * 8 + (x >> 1)] = (u32)pk;
                }
            }
        }
#pragma unroll
        for (int it = 0; it < 4; ++it) {
            int rr = (l >> 4) + it * 4;
            int row = rbase + rr;
            if (row < Np) {
                uint4 v = *(const uint4*)&tile[wave][rr][(l & 15) * 4];
                *(uint4*)(km8 + (size_t)row * 64 + (l & 15) * 4) = v;
            }
        }
    }
}

// ---------------------------------------------------------------------------
// P5: CSR aggregation: one wave per destination, 8-edge unrolled, fp8 payload.
// ---------------------------------------------------------------------------
__device__ inline void e_acc(u32 km, float2 qf, float muh,
                             float& dsum, float& a0, float& a1)
{
    f32x2 kf = __builtin_amdgcn_cvt_pk_f32_fp8(km, false);
    f32x2 mf = __builtin_amdgcn_cvt_pk_f32_fp8(km, true);
    float p = kf.x * qf.x + kf.y * qf.y;
    p += __shfl_xor(p, 1, 16);
    p += __shfl_xor(p, 2, 16);
    p += __shfl_xor(p, 4, 16);
    p += __shfl_xor(p, 8, 16);
    float ev = __expf(p * muh);
    dsum += ev; a0 += ev * mf.x; a1 += ev * mf.y;
}

__global__ __launch_bounds__(256) void csr_agg(
    const u32* __restrict__ km8, const u32* __restrict__ qap,
    const int* __restrict__ rowptr, const int* __restrict__ csrc,
    const float* __restrict__ mu1, u32* __restrict__ gagg, int Na)
{
    int dst = blockIdx.x * 4 + (threadIdx.x >> 6);
    if (dst >= Na) return;
    int lane = threadIdx.x & 63;
    int h = lane >> 4;
    float muh = mu1[h] * 0.17677669529663689f * FP8_INV;  // mu/sqrt(32)/S
    float2 qf = bf2f2(qap[(size_t)dst * 64 + lane]);

    float a0 = 0.f, a1 = 0.f, dsum = 0.f;
    int beg = rowptr[dst], end = rowptr[dst + 1];

    int i = beg;
    for (; i + 8 <= end; i += 8) {
        int s[8];
        u32 km[8];
#pragma unroll
        for (int j = 0; j < 8; ++j) s[j] = csrc[i + j];
#pragma unroll
        for (int j = 0; j < 8; ++j) km[j] = km8[(size_t)s[j] * 64 + lane];
#pragma unroll
        for (int j = 0; j < 8; ++j) e_acc(km[j], qf, muh, dsum, a0, a1);
    }
    for (; i + 4 <= end; i += 4) {
        int s0 = csrc[i], s1 = csrc[i + 1], s2 = csrc[i + 2], s3 = csrc[i + 3];
        u32 km0 = km8[(size_t)s0 * 64 + lane];
        u32 km1 = km8[(size_t)s1 * 64 + lane];
        u32 km2 = km8[(size_t)s2 * 64 + lane];
        u32 km3 = km8[(size_t)s3 * 64 + lane];
        e_acc(km0, qf, muh, dsum, a0, a1);
        e_acc(km1, qf, muh, dsum, a0, a1);
        e_acc(km2, qf, muh, dsum, a0, a1);
        e_acc(km3, qf, muh, dsum, a0, a1);
    }
    for (; i < end; ++i) {
        u32 km0 = km8[(size_t)csrc[i] * 64 + lane];
        e_acc(km0, qf, muh, dsum, a0, a1);
    }
    float dn = dsum + 1e-9f;
    a0 = gelu_t(a0 / dn * FP8_INV);
    a1 = gelu_t(a1 / dn * FP8_INV);
    gagg[(size_t)dst * 64 + lane] = ((u32)f2bf(a1) << 16) | (u32)f2bf(a0);
}

// ---------------------------------------------------------------------------
// P6: out = gagg@w1T + xa@lwT + lin_b  (bf16 in, f32 out, LDS-staged stores)
// ---------------------------------------------------------------------------
__global__ __launch_bounds__(256) void mfma_out(
    const u16* __restrict__ A0, const u16* __restrict__ WT0,
    const u16* __restrict__ A1, const u16* __restrict__ WT1,
    const float* __restrict__ bias, float* __restrict__ Y, int N)
{
    __shared__ float tile[4][16][128];   // 32 KB: per-wave 16x512B staging
    int wave = threadIdx.x >> 6;
    int l = threadIdx.x & 63;
    int rbase = blockIdx.x * 64 + wave * 16;
    int arow = rbase + (l & 15);
    if (arow >= N) arow = N - 1;
    int kb = (l >> 4) * 8;

    f32x4 acc[8];
#pragma unroll
    for (int ct = 0; ct < 8; ++ct) acc[ct] = (f32x4){0.f, 0.f, 0.f, 0.f};

    for (int w = 0; w < 2; ++w) {
        const u16* A  = w ? A1 : A0;
        const u16* WT = w ? WT1 : WT0;
        bf16x8 af[4];
#pragma unroll
        for (int ks = 0; ks < 4; ++ks)
            af[ks] = *(const bf16x8*)(A + (size_t)arow * 128 + ks * 32 + kb);
#pragma unroll
        for (int ks = 0; ks < 4; ++ks) {
#pragma unroll
            for (int ct = 0; ct < 8; ++ct) {
                bf16x8 bf = *(const bf16x8*)(WT + (size_t)(ct * 16 + (l & 15)) * 128 + ks * 32 + kb);
                acc[ct] = __builtin_amdgcn_mfma_f32_16x16x32_bf16(af[ks], bf, acc[ct], 0, 0, 0);
            }
        }
    }
    // stage into private LDS slice (bias applied here)
#pragma unroll
    for (int ct = 0; ct < 8; ++ct) {
        int col = ct * 16 + (l & 15);
        float b = bias[col];
#pragma unroll
        for (int r = 0; r < 4; ++r) {
            int rr = ((l >> 4) << 2) + r;
            tile[wave][rr][col] = acc[ct][r] + b;
        }
    }
    // coalesced write-out: 2 consecutive rows (1 KB) per iteration
#pragma unroll
    for (int it = 0; it < 8; ++it) {
        int rr = (l >> 5) + it * 2;
        int row = rbase + rr;
        if (row < N) {
            float4 v = *(const float4*)&tile[wave][rr][(l & 31) * 4];
            *(float4*)(Y + (size_t)row * 128 + (l & 31) * 4) = v;
        }
    }
}

// ---------------------------------------------------------------------------
extern "C" void kernel_launch(void* const* d_in, const int* in_sizes, int n_in,
                              void* d_out, int out_size, void* d_ws, size_t ws_size,
                              hipStream_t stream)
{
    const int*   tok_a   = (const int*)d_in[0];
    const int*   tok_p   = (const int*)d_in[1];
    const int*   edge_pa = (const int*)d_in[3];
    const float* emb     = (const float*)d_in[4];
    const float* Wk      = (const float*)d_in[5];
    const float* Wq      = (const float*)d_in[6];
    const float* Wv      = (const float*)d_in[7];
    const float* Watt    = (const float*)d_in[8];
    const float* Wmsg    = (const float*)d_in[9];
    const float* mu      = (const float*)d_in[10];
    const float* Wout    = (const float*)d_in[11];
    const float* lin_w   = (const float*)d_in[12];
    const float* lin_b   = (const float*)d_in[13];

    int Na = in_sizes[0] / L;
    int Np = in_sizes[1] / L;
    int E  = in_sizes[3] / 2;
    int V  = in_sizes[4] / 128;
    float* out = (float*)d_out;

    // workspace layout (all segments 16B-aligned)
    u16* xa      = (u16*)d_ws;                      // Na*128 bf16
    u16* qa      = xa + (size_t)Na * 128;           // Na*128 bf16
    u16* xp      = qa + (size_t)Na * 128;           // Np*128 bf16
    u16* gagg    = xp + (size_t)Np * 128;           // Na*128 bf16 (written P5)
    u16* emb_bf  = gagg + (size_t)Na * 128;         // V*128 bf16
    u32* km8     = (u32*)(emb_bf + (size_t)V * 128);// Np*64 u32 (fp8 packed)
    int* deg     = (int*)(km8 + (size_t)Np * 64);   // Na
    int* locpref = deg + Na;                        // Na
    int* rowptr  = locpref + Na;                    // Na+2
    int* csrc    = rowptr + Na + 2;                 // E
    int* blocksum= csrc + E;                        // 256
    u16* wkaT    = (u16*)(blocksum + 256);          // 16384 bf16 each
    u16* wvmT    = wkaT + 16384;
    u16* wqT     = wvmT + 16384;
    u16* w1T     = wqT + 16384;
    u16* lwT     = w1T + 16384;
    // rank aliases gagg: rank live P1->P4, gagg written first in P5.
    int* rank    = (int*)gagg;

    const int* e_src = edge_pa;
    const int* e_dst = edge_pa + E;

    int n2emb   = V * 64;
    int Bconv   = (n2emb + 255) / 256;
    int Bzero   = (Na + 255) / 256;
    int Bfold   = (5 * 16384) / 256;
    int Bhist8  = (E + 2047) / 2048;
    int hstride = Bhist8 * 256;
    int nb      = (Na + 1023) / 1024;   // <= 256
    int Ntot    = Na + Np;
    int Benc    = ((size_t)Ntot * 16 + 255) / 256;
    int BscanF  = (Na + 255) / 256;
    int gba     = (Na + 63) / 64;
    int gbp     = (Np + 63) / 64;
    int Bproj   = gba + gbp;
    int Bscat8  = (E + 2047) / 2048;
    int sstride = Bscat8 * 256;

    // P0: zero deg | emb -> bf16
    k_zero_conv<<<Bzero + Bconv, 256, 0, stream>>>(
        deg, Na, Bzero, emb, (u32*)emb_bf, n2emb);

    // P1: hist (ILP8 + rank) | weight folding | node encoding (long pole)
    k_prep<<<Bhist8 + Bfold + Benc, 256, 0, stream>>>(
        e_dst, deg, rank, E, Bhist8, hstride,
        Wk + 16384, Wq, Wv + 16384, Watt + 4096, Wmsg + 4096, Wout, lin_w,
        wkaT, wvmT, wqT, w1T, lwT, Bfold,
        tok_a, tok_p, (const uint4*)emb_bf, (uint4*)xa, (uint4*)xp, Na, Ntot);

    // P2: local scan
    k_scan<<<nb, 256, 0, stream>>>(deg, locpref, blocksum, Na);

    // P3: rowptr finalize (redundant in-block scan of blocksums)
    k_final<<<BscanF, 256, 0, stream>>>(locpref, blocksum, rowptr, nb, Na);

    // P4: rank-scatter (ILP8) | MFMA projections — round-robin interleaved
    int Gunit = (Bscat8 > (Bproj + 1) / 2) ? Bscat8 : (Bproj + 1) / 2;
    k_scat_proj<<<3 * Gunit, 256, 0, stream>>>(
        e_src, e_dst, rank, rowptr, csrc, E, Bscat8, sstride,
        xa, xp, wqT, wkaT, wvmT, qa, km8, Na, Np, gba, Bproj);

    // P5: CSR aggregation (softmax + weighted sum + normalize + gelu)
    csr_agg<<<(Na + 3) / 4, 256, 0, stream>>>(
        km8, (const u32*)qa, rowptr, csrc, mu + 4, (u32*)gagg, Na);

    // P6: out = gagg@w1T + xa@lwT + lin_b
    mfma_out<<<gba, 256, 0, stream>>>(gagg, w1T, xa, lwT, lin_b, out, Na);
}

// Round 18
// 194.066 us; speedup vs baseline: 1.0210x; 1.0210x over previous
//
#include <hip/hip_runtime.h>
#include <math.h>

#define L 8
#define FP8_SCALE 512.0f
#define FP8_INV   0.001953125f   // 1/512

typedef unsigned int  u32;
typedef unsigned short u16;
typedef __attribute__((ext_vector_type(8))) short bf16x8;
typedef __attribute__((ext_vector_type(4))) float f32x4;
typedef __attribute__((ext_vector_type(2))) float f32x2;

// fp32 -> bf16 round-to-nearest-even
__device__ inline u16 f2bf(float x) {
    u32 u = __float_as_uint(x);
    return (u16)((u + 0x7fffu + ((u >> 16) & 1u)) >> 16);
}
// unpack 2 packed bf16 (low = even elem, high = odd elem)
__device__ inline float2 bf2f2(u32 v) {
    float2 r;
    r.x = __uint_as_float(v << 16);
    r.y = __uint_as_float(v & 0xffff0000u);
    return r;
}
__device__ inline float gelu_t(float x) {
    return 0.5f * x * (1.0f + tanhf(0.7978845608028654f *
           (x + 0.044715f * x * x * x)));
}

// ---------------------------------------------------------------------------
// Device bodies
// ---------------------------------------------------------------------------
__device__ inline void zero_body(int bid, int tid, int* __restrict__ deg, int Na)
{
    int i = bid * 256 + tid;
    if (i < Na) deg[i] = 0;
}

__device__ inline void conv_emb_body(int bid, int tid,
    const float* __restrict__ emb, u32* __restrict__ emb_bf, int n2)
{
    int i = bid * 256 + tid;
    if (i >= n2) return;
    float2 e = *(const float2*)(emb + (size_t)i * 2);
    emb_bf[i] = ((u32)f2bf(e.y) << 16) | (u32)f2bf(e.x);
}

// ILP-8 degree histogram WITH rank capture: rank[e] = old count of dst bucket.
__device__ inline void hist_body8(int bid, int tid,
    const int* __restrict__ dstI, int* __restrict__ deg,
    int* __restrict__ rank, int E, int stride)
{
    int e0 = bid * 256 + tid;
    int d[8], r[8];
#pragma unroll
    for (int j = 0; j < 8; ++j) {
        int e = e0 + j * stride;
        d[j] = (e < E) ? dstI[e] : -1;
    }
#pragma unroll
    for (int j = 0; j < 8; ++j)
        r[j] = (d[j] >= 0) ? atomicAdd(&deg[d[j]], 1) : 0;
#pragma unroll
    for (int j = 0; j < 8; ++j) {
        int e = e0 + j * stride;
        if (d[j] >= 0) rank[e] = r[j];
    }
}

__device__ inline void fold_body(int bid, int tid,
    const float* __restrict__ Wk1, const float* __restrict__ Wq0,
    const float* __restrict__ Wv1, const float* __restrict__ Watt1,
    const float* __restrict__ Wmsg1, const float* __restrict__ Wout0,
    const float* __restrict__ lin_w,
    u16* __restrict__ wkaT, u16* __restrict__ wvmT,
    u16* __restrict__ wqT, u16* __restrict__ w1T, u16* __restrict__ lwT)
{
    int id = bid * 256 + tid;   // < 5*16384
    int which = id >> 14;
    int idx = id & 16383;
    int col = idx & 127;
    int k = idx >> 7;
    if (which == 0) {
        int h = col >> 5, f = col & 31;
        float s = 0.f;
        for (int d = 0; d < 32; ++d)
            s += Wk1[k * 128 + h * 32 + d] * Watt1[h * 1024 + d * 32 + f];
        wkaT[col * 128 + k] = f2bf(s);
    } else if (which == 1) {
        int h = col >> 5, f = col & 31;
        float s = 0.f;
        for (int d = 0; d < 32; ++d)
            s += Wv1[k * 128 + h * 32 + d] * Wmsg1[h * 1024 + d * 32 + f];
        wvmT[col * 128 + k] = f2bf(s);
    } else if (which == 2) {
        wqT[col * 128 + k] = f2bf(Wq0[k * 128 + col]);
    } else if (which == 3) {
        float s = 0.f;
        for (int d = 0; d < 128; ++d)
            s += Wout0[k * 128 + d] * lin_w[d * 128 + col];
        w1T[col * 128 + k] = f2bf(s);
    } else {
        lwT[col * 128 + k] = f2bf(lin_w[k * 128 + col]);
    }
}

// node encode: 16 threads/node, uint4 (8 dims, 16B) per lane, int4 token loads.
__device__ inline void encode_body(int bid, int tid,
    const int* __restrict__ tok_a, const int* __restrict__ tok_p,
    const uint4* __restrict__ emb_bf4,
    uint4* __restrict__ xa4, uint4* __restrict__ xp4, int Na, int Ntot)
{
    int i = bid * 256 + tid;
    int n = i >> 4, q = i & 15;
    if (n >= Ntot) return;
    const int* tok = (n < Na) ? (tok_a + (size_t)n * L)
                              : (tok_p + (size_t)(n - Na) * L);
    int4 t0 = *(const int4*)tok;
    int4 t1 = *(const int4*)(tok + 4);
    int tt[8] = {t0.x, t0.y, t0.z, t0.w, t1.x, t1.y, t1.z, t1.w};
    float a[8] = {0.f, 0.f, 0.f, 0.f, 0.f, 0.f, 0.f, 0.f};
    int cnt = 0;
#pragma unroll
    for (int l = 0; l < L; ++l) {
        int t = tt[l];
        if (t != 0) {
            cnt++;
            uint4 e = emb_bf4[(size_t)t * 16 + q];
            float2 e0 = bf2f2(e.x), e1 = bf2f2(e.y);
            float2 e2 = bf2f2(e.z), e3 = bf2f2(e.w);
            a[0] += e0.x; a[1] += e0.y; a[2] += e1.x; a[3] += e1.y;
            a[4] += e2.x; a[5] += e2.y; a[6] += e3.x; a[7] += e3.y;
        }
    }
    float dn = 1.0f / fmaxf((float)cnt, 1.0f);
#pragma unroll
    for (int j = 0; j < 8; ++j) a[j] = fmaxf(a[j] * dn, 0.f);
    uint4 o;
    o.x = ((u32)f2bf(a[1]) << 16) | (u32)f2bf(a[0]);
    o.y = ((u32)f2bf(a[3]) << 16) | (u32)f2bf(a[2]);
    o.z = ((u32)f2bf(a[5]) << 16) | (u32)f2bf(a[4]);
    o.w = ((u32)f2bf(a[7]) << 16) | (u32)f2bf(a[6]);
    if (n < Na) xa4[(size_t)n * 16 + q] = o;
    else        xp4[(size_t)(n - Na) * 16 + q] = o;
}

// ILP-8 rank-based scatter: NO atomics. csrc[rowptr[dst]+rank] = src.
__device__ inline void scatter_body8(int bid, int tid,
    const int* __restrict__ srcI, const int* __restrict__ dstI,
    const int* __restrict__ rank, const int* __restrict__ rowptr,
    int* __restrict__ csrc, int E, int stride)
{
    int e0 = bid * 256 + tid;
    int d[8], s[8], r[8];
#pragma unroll
    for (int j = 0; j < 8; ++j) {
        int e = e0 + j * stride;
        d[j] = (e < E) ? dstI[e] : -1;
        s[j] = (e < E) ? srcI[e] : 0;
        r[j] = (e < E) ? rank[e] : 0;
    }
    int base[8];
#pragma unroll
    for (int j = 0; j < 8; ++j)
        base[j] = (d[j] >= 0) ? rowptr[d[j]] : 0;
#pragma unroll
    for (int j = 0; j < 8; ++j)
        if (d[j] >= 0) csrc[base[j] + r[j]] = s[j];
}

// ---------------------------------------------------------------------------
// Packed kernels
// ---------------------------------------------------------------------------
// P0: zero deg | emb fp32 -> bf16
__global__ __launch_bounds__(256) void k_zero_conv(
    int* deg, int Na, int Bzero,
    const float* emb, u32* emb_bf, int n2)
{
    int b = blockIdx.x, t = threadIdx.x;
    if (b < Bzero) zero_body(b, t, deg, Na);
    else           conv_emb_body(b - Bzero, t, emb, emb_bf, n2);
}

// P1: hist (ILP8 + rank) | weight fold | node ENCODE (the long pole).
__global__ __launch_bounds__(256) void k_prep(
    const int* dstI, int* deg, int* rank, int E, int Bhist8, int stride,
    const float* Wk1, const float* Wq0, const float* Wv1,
    const float* Watt1, const float* Wmsg1, const float* Wout0,
    const float* lin_w, u16* wkaT, u16* wvmT, u16* wqT, u16* w1T, u16* lwT,
    int Bfold,
    const int* tok_a, const int* tok_p, const uint4* emb_bf4,
    uint4* xa4, uint4* xp4, int Na, int Ntot)
{
    int b = blockIdx.x, t = threadIdx.x;
    if (b < Bhist8)               hist_body8(b, t, dstI, deg, rank, E, stride);
    else if (b < Bhist8 + Bfold)  fold_body(b - Bhist8, t, Wk1, Wq0, Wv1,
                                      Watt1, Wmsg1, Wout0, lin_w,
                                      wkaT, wvmT, wqT, w1T, lwT);
    else encode_body(b - Bhist8 - Bfold, t, tok_a, tok_p, emb_bf4,
                     xa4, xp4, Na, Ntot);
}

// P2: per-block scan over 1024 degrees -> local prefixes + block total
__global__ __launch_bounds__(256) void k_scan(
    const int* __restrict__ deg, int* __restrict__ locpref,
    int* __restrict__ blocksum, int Na)
{
    __shared__ int lds[256];
    int tid = threadIdx.x;
    int base = blockIdx.x * 1024 + tid * 4;
    int4 v = {0, 0, 0, 0};
    if (base + 3 < Na) {
        v = *(const int4*)(deg + base);
    } else {
        if (base + 0 < Na) v.x = deg[base + 0];
        if (base + 1 < Na) v.y = deg[base + 1];
        if (base + 2 < Na) v.z = deg[base + 2];
        if (base + 3 < Na) v.w = deg[base + 3];
    }
    int tot = v.x + v.y + v.z + v.w;
    lds[tid] = tot;
    __syncthreads();
    for (int off = 1; off < 256; off <<= 1) {
        int u = (tid >= off) ? lds[tid - off] : 0;
        __syncthreads();
        lds[tid] += u;
        __syncthreads();
    }
    int excl = lds[tid] - tot;
    if (base < Na) {
        int4 o;
        o.x = excl;
        o.y = excl + v.x;
        o.z = o.y + v.y;
        o.w = o.z + v.z;
        if (base + 3 < Na) *(int4*)(locpref + base) = o;
        else {
            locpref[base] = o.x;
            if (base + 1 < Na) locpref[base + 1] = o.y;
            if (base + 2 < Na) locpref[base + 2] = o.z;
        }
    }
    if (tid == 255) blocksum[blockIdx.x] = lds[255];
}

// P3: rowptr finalize — every block redundantly scans the <=256 block sums.
__global__ __launch_bounds__(256) void k_final(
    const int* __restrict__ locpref, const int* __restrict__ blocksum,
    int* __restrict__ rowptr, int nb, int Na)
{
    __shared__ int lds[256];
    __shared__ int excl[256];
    int t = threadIdx.x;
    int s = (t < nb) ? blocksum[t] : 0;
    lds[t] = s;
    __syncthreads();
    for (int off = 1; off < 256; off <<= 1) {
        int u = (t >= off) ? lds[t - off] : 0;
        __syncthreads();
        lds[t] += u;
        __syncthreads();
    }
    excl[t] = lds[t] - s;
    __syncthreads();
    int i = blockIdx.x * 256 + t;
    if (i < Na)
        rowptr[i] = locpref[i] + excl[i >> 10];
    if (blockIdx.x == 0 && t == 0)
        rowptr[Na] = lds[nb - 1];
}

// ---------------------------------------------------------------------------
// P4: rank-scatter (ILP8) | MFMA projection — round-robin interleaved.
// Proj waves HALVED: each wave covers 16 rows x 64 cols (16/32 MFMA) so proj
// and scatter waves have comparable duration -> shorter drain tail, finer
// scheduling granularity. Bproj2 = 2*(gba+gbp); pb>>1 = tile, pb&1 = col half.
// proj role 0: qa = xa @ wqT (bf16 direct stores)
// proj role 1: kacc/macc in regs -> packed fp8 km8 direct
// ---------------------------------------------------------------------------
__global__ __launch_bounds__(256) void k_scat_proj(
    const int* srcI, const int* dstI, const int* rank, const int* rowptr,
    int* csrc, int E, int Bscat8, int stride,
    const u16* __restrict__ xa, const u16* __restrict__ xp,
    const u16* __restrict__ wqT, const u16* __restrict__ wkaT,
    const u16* __restrict__ wvmT,
    u16* __restrict__ qa, u32* __restrict__ km8, int Na, int Np, int gba,
    int Bproj2)
{
    int b = blockIdx.x, t = threadIdx.x;
    if (b % 3 == 0) {
        int sb = b / 3;
        if (sb < Bscat8)
            scatter_body8(sb, t, srcI, dstI, rank, rowptr, csrc, E, stride);
        return;
    }
    int pb = (b / 3) * 2 + (b % 3 - 1);
    if (pb >= Bproj2) return;
    int tilei = pb >> 1;
    int half = pb & 1;
    int cbase = half * 64;

    int wave = t >> 6;
    int l = t & 63;
    int x = l & 15;
    int kb = (l >> 4) * 8;

    if (tilei < gba) {
        // ---- author: qa[:, cbase:cbase+64] = xa @ wqT[cbase:...] ----
        int rbase = tilei * 64 + wave * 16;
        int arow = rbase + x;
        if (arow >= Na) arow = Na - 1;
        bf16x8 af[4];
#pragma unroll
        for (int ks = 0; ks < 4; ++ks)
            af[ks] = *(const bf16x8*)(xa + (size_t)arow * 128 + ks * 32 + kb);
        f32x4 acc[4];
#pragma unroll
        for (int ct = 0; ct < 4; ++ct) acc[ct] = (f32x4){0.f, 0.f, 0.f, 0.f};
#pragma unroll
        for (int ks = 0; ks < 4; ++ks)
#pragma unroll
            for (int ct = 0; ct < 4; ++ct) {
                bf16x8 bf = *(const bf16x8*)(wqT + (size_t)(cbase + ct * 16 + x) * 128 + ks * 32 + kb);
                acc[ct] = __builtin_amdgcn_mfma_f32_16x16x32_bf16(af[ks], bf, acc[ct], 0, 0, 0);
            }
        int srow = rbase + ((l >> 4) << 2);
#pragma unroll
        for (int ct = 0; ct < 4; ++ct) {
            int col = cbase + ct * 16 + x;
#pragma unroll
            for (int r = 0; r < 4; ++r)
                if (srow + r < Na)
                    qa[(size_t)(srow + r) * 128 + col] = f2bf(acc[ct][r]);
        }
    } else {
        // ---- paper: kacc/macc -> fp8 km8 direct ----
        int b2 = tilei - gba;
        int rbase = b2 * 64 + wave * 16;
        int arow = rbase + x;
        if (arow >= Np) arow = Np - 1;
        bf16x8 af[4];
#pragma unroll
        for (int ks = 0; ks < 4; ++ks)
            af[ks] = *(const bf16x8*)(xp + (size_t)arow * 128 + ks * 32 + kb);
        f32x4 kacc[4], macc[4];
#pragma unroll
        for (int ct = 0; ct < 4; ++ct) {
            kacc[ct] = (f32x4){0.f, 0.f, 0.f, 0.f};
            macc[ct] = (f32x4){0.f, 0.f, 0.f, 0.f};
        }
#pragma unroll
        for (int ks = 0; ks < 4; ++ks)
#pragma unroll
            for (int ct = 0; ct < 4; ++ct) {
                bf16x8 bk = *(const bf16x8*)(wkaT + (size_t)(cbase + ct * 16 + x) * 128 + ks * 32 + kb);
                kacc[ct] = __builtin_amdgcn_mfma_f32_16x16x32_bf16(af[ks], bk, kacc[ct], 0, 0, 0);
            }
#pragma unroll
        for (int ks = 0; ks < 4; ++ks)
#pragma unroll
            for (int ct = 0; ct < 4; ++ct) {
                bf16x8 bm = *(const bf16x8*)(wvmT + (size_t)(cbase + ct * 16 + x) * 128 + ks * 32 + kb);
                macc[ct] = __builtin_amdgcn_mfma_f32_16x16x32_bf16(af[ks], bm, macc[ct], 0, 0, 0);
            }
        int srow = rbase + ((l >> 4) << 2);
#pragma unroll
        for (int ct = 0; ct < 4; ++ct) {
#pragma unroll
            for (int r = 0; r < 4; ++r) {
                float k0 = kacc[ct][r] * FP8_SCALE;
                float k1 = __shfl_xor(k0, 1);
                float m0 = macc[ct][r] * FP8_SCALE;
                float m1 = __shfl_xor(m0, 1);
                if (!(x & 1) && (srow + r) < Np) {
                    int pk = __builtin_amdgcn_cvt_pk_fp8_f32(k0, k1, 0, false);
                    pk = __builtin_amdgcn_cvt_pk_fp8_f32(m0, m1, pk, true);
                    km8[(size_t)(srow + r) * 64 + half * 32 + ct * 8 + (x >> 1)] = (u32)pk;
                }
            }
        }
    }
}

// ---------------------------------------------------------------------------
// P5: CSR aggregation: one wave per destination, 8-edge unrolled, fp8 payload.
// ---------------------------------------------------------------------------
__device__ inline void e_acc(u32 km, float2 qf, float muh,
                             float& dsum, float& a0, float& a1)
{
    f32x2 kf = __builtin_amdgcn_cvt_pk_f32_fp8(km, false);
    f32x2 mf = __builtin_amdgcn_cvt_pk_f32_fp8(km, true);
    float p = kf.x * qf.x + kf.y * qf.y;
    p += __shfl_xor(p, 1, 16);
    p += __shfl_xor(p, 2, 16);
    p += __shfl_xor(p, 4, 16);
    p += __shfl_xor(p, 8, 16);
    float ev = __expf(p * muh);
    dsum += ev; a0 += ev * mf.x; a1 += ev * mf.y;
}

__global__ __launch_bounds__(256) void csr_agg(
    const u32* __restrict__ km8, const u32* __restrict__ qap,
    const int* __restrict__ rowptr, const int* __restrict__ csrc,
    const float* __restrict__ mu1, u32* __restrict__ gagg, int Na)
{
    int dst = blockIdx.x * 4 + (threadIdx.x >> 6);
    if (dst >= Na) return;
    int lane = threadIdx.x & 63;
    int h = lane >> 4;
    float muh = mu1[h] * 0.17677669529663689f * FP8_INV;  // mu/sqrt(32)/S
    float2 qf = bf2f2(qap[(size_t)dst * 64 + lane]);

    float a0 = 0.f, a1 = 0.f, dsum = 0.f;
    int beg = rowptr[dst], end = rowptr[dst + 1];

    int i = beg;
    for (; i + 8 <= end; i += 8) {
        int s[8];
        u32 km[8];
#pragma unroll
        for (int j = 0; j < 8; ++j) s[j] = csrc[i + j];
#pragma unroll
        for (int j = 0; j < 8; ++j) km[j] = km8[(size_t)s[j] * 64 + lane];
#pragma unroll
        for (int j = 0; j < 8; ++j) e_acc(km[j], qf, muh, dsum, a0, a1);
    }
    for (; i + 4 <= end; i += 4) {
        int s0 = csrc[i], s1 = csrc[i + 1], s2 = csrc[i + 2], s3 = csrc[i + 3];
        u32 km0 = km8[(size_t)s0 * 64 + lane];
        u32 km1 = km8[(size_t)s1 * 64 + lane];
        u32 km2 = km8[(size_t)s2 * 64 + lane];
        u32 km3 = km8[(size_t)s3 * 64 + lane];
        e_acc(km0, qf, muh, dsum, a0, a1);
        e_acc(km1, qf, muh, dsum, a0, a1);
        e_acc(km2, qf, muh, dsum, a0, a1);
        e_acc(km3, qf, muh, dsum, a0, a1);
    }
    for (; i < end; ++i) {
        u32 km0 = km8[(size_t)csrc[i] * 64 + lane];
        e_acc(km0, qf, muh, dsum, a0, a1);
    }
    float dn = dsum + 1e-9f;
    a0 = gelu_t(a0 / dn * FP8_INV);
    a1 = gelu_t(a1 / dn * FP8_INV);
    gagg[(size_t)dst * 64 + lane] = ((u32)f2bf(a1) << 16) | (u32)f2bf(a0);
}

// ---------------------------------------------------------------------------
// P6: out = gagg@w1T + xa@lwT + lin_b  (bf16 in, f32 out, LDS-staged stores)
// ---------------------------------------------------------------------------
__global__ __launch_bounds__(256) void mfma_out(
    const u16* __restrict__ A0, const u16* __restrict__ WT0,
    const u16* __restrict__ A1, const u16* __restrict__ WT1,
    const float* __restrict__ bias, float* __restrict__ Y, int N)
{
    __shared__ float tile[4][16][128];   // 32 KB: per-wave 16x512B staging
    int wave = threadIdx.x >> 6;
    int l = threadIdx.x & 63;
    int rbase = blockIdx.x * 64 + wave * 16;
    int arow = rbase + (l & 15);
    if (arow >= N) arow = N - 1;
    int kb = (l >> 4) * 8;

    f32x4 acc[8];
#pragma unroll
    for (int ct = 0; ct < 8; ++ct) acc[ct] = (f32x4){0.f, 0.f, 0.f, 0.f};

    for (int w = 0; w < 2; ++w) {
        const u16* A  = w ? A1 : A0;
        const u16* WT = w ? WT1 : WT0;
        bf16x8 af[4];
#pragma unroll
        for (int ks = 0; ks < 4; ++ks)
            af[ks] = *(const bf16x8*)(A + (size_t)arow * 128 + ks * 32 + kb);
#pragma unroll
        for (int ks = 0; ks < 4; ++ks) {
#pragma unroll
            for (int ct = 0; ct < 8; ++ct) {
                bf16x8 bf = *(const bf16x8*)(WT + (size_t)(ct * 16 + (l & 15)) * 128 + ks * 32 + kb);
                acc[ct] = __builtin_amdgcn_mfma_f32_16x16x32_bf16(af[ks], bf, acc[ct], 0, 0, 0);
            }
        }
    }
    // stage into private LDS slice (bias applied here)
#pragma unroll
    for (int ct = 0; ct < 8; ++ct) {
        int col = ct * 16 + (l & 15);
        float b = bias[col];
#pragma unroll
        for (int r = 0; r < 4; ++r) {
            int rr = ((l >> 4) << 2) + r;
            tile[wave][rr][col] = acc[ct][r] + b;
        }
    }
    // coalesced write-out: 2 consecutive rows (1 KB) per iteration
#pragma unroll
    for (int it = 0; it < 8; ++it) {
        int rr = (l >> 5) + it * 2;
        int row = rbase + rr;
        if (row < N) {
            float4 v = *(const float4*)&tile[wave][rr][(l & 31) * 4];
            *(float4*)(Y + (size_t)row * 128 + (l & 31) * 4) = v;
        }
    }
}

// ---------------------------------------------------------------------------
extern "C" void kernel_launch(void* const* d_in, const int* in_sizes, int n_in,
                              void* d_out, int out_size, void* d_ws, size_t ws_size,
                              hipStream_t stream)
{
    const int*   tok_a   = (const int*)d_in[0];
    const int*   tok_p   = (const int*)d_in[1];
    const int*   edge_pa = (const int*)d_in[3];
    const float* emb     = (const float*)d_in[4];
    const float* Wk      = (const float*)d_in[5];
    const float* Wq      = (const float*)d_in[6];
    const float* Wv      = (const float*)d_in[7];
    const float* Watt    = (const float*)d_in[8];
    const float* Wmsg    = (const float*)d_in[9];
    const float* mu      = (const float*)d_in[10];
    const float* Wout    = (const float*)d_in[11];
    const float* lin_w   = (const float*)d_in[12];
    const float* lin_b   = (const float*)d_in[13];

    int Na = in_sizes[0] / L;
    int Np = in_sizes[1] / L;
    int E  = in_sizes[3] / 2;
    int V  = in_sizes[4] / 128;
    float* out = (float*)d_out;

    // workspace layout (all segments 16B-aligned)
    u16* xa      = (u16*)d_ws;                      // Na*128 bf16
    u16* qa      = xa + (size_t)Na * 128;           // Na*128 bf16
    u16* xp      = qa + (size_t)Na * 128;           // Np*128 bf16
    u16* gagg    = xp + (size_t)Np * 128;           // Na*128 bf16 (written P5)
    u16* emb_bf  = gagg + (size_t)Na * 128;         // V*128 bf16
    u32* km8     = (u32*)(emb_bf + (size_t)V * 128);// Np*64 u32 (fp8 packed)
    int* deg     = (int*)(km8 + (size_t)Np * 64);   // Na
    int* locpref = deg + Na;                        // Na
    int* rowptr  = locpref + Na;                    // Na+2
    int* csrc    = rowptr + Na + 2;                 // E
    int* blocksum= csrc + E;                        // 256
    u16* wkaT    = (u16*)(blocksum + 256);          // 16384 bf16 each
    u16* wvmT    = wkaT + 16384;
    u16* wqT     = wvmT + 16384;
    u16* w1T     = wqT + 16384;
    u16* lwT     = w1T + 16384;
    // rank aliases gagg: rank live P1->P4, gagg written first in P5.
    int* rank    = (int*)gagg;

    const int* e_src = edge_pa;
    const int* e_dst = edge_pa + E;

    int n2emb   = V * 64;
    int Bconv   = (n2emb + 255) / 256;
    int Bzero   = (Na + 255) / 256;
    int Bfold   = (5 * 16384) / 256;
    int Bhist8  = (E + 2047) / 2048;
    int hstride = Bhist8 * 256;
    int nb      = (Na + 1023) / 1024;   // <= 256
    int Ntot    = Na + Np;
    int Benc    = ((size_t)Ntot * 16 + 255) / 256;
    int BscanF  = (Na + 255) / 256;
    int gba     = (Na + 63) / 64;
    int gbp     = (Np + 63) / 64;
    int Bproj2  = 2 * (gba + gbp);      // half-column proj tiles
    int Bscat8  = (E + 2047) / 2048;
    int sstride = Bscat8 * 256;

    // P0: zero deg | emb -> bf16
    k_zero_conv<<<Bzero + Bconv, 256, 0, stream>>>(
        deg, Na, Bzero, emb, (u32*)emb_bf, n2emb);

    // P1: hist (ILP8 + rank) | weight folding | node encoding (long pole)
    k_prep<<<Bhist8 + Bfold + Benc, 256, 0, stream>>>(
        e_dst, deg, rank, E, Bhist8, hstride,
        Wk + 16384, Wq, Wv + 16384, Watt + 4096, Wmsg + 4096, Wout, lin_w,
        wkaT, wvmT, wqT, w1T, lwT, Bfold,
        tok_a, tok_p, (const uint4*)emb_bf, (uint4*)xa, (uint4*)xp, Na, Ntot);

    // P2: local scan
    k_scan<<<nb, 256, 0, stream>>>(deg, locpref, blocksum, Na);

    // P3: rowptr finalize (redundant in-block scan of blocksums)
    k_final<<<BscanF, 256, 0, stream>>>(locpref, blocksum, rowptr, nb, Na);

    // P4: rank-scatter (ILP8) | MFMA projections (half-column waves)
    int Gunit = (Bscat8 > (Bproj2 + 1) / 2) ? Bscat8 : (Bproj2 + 1) / 2;
    k_scat_proj<<<3 * Gunit, 256, 0, stream>>>(
        e_src, e_dst, rank, rowptr, csrc, E, Bscat8, sstride,
        xa, xp, wqT, wkaT, wvmT, qa, km8, Na, Np, gba, Bproj2);

    // P5: CSR aggregation (softmax + weighted sum + normalize + gelu)
    csr_agg<<<(Na + 3) / 4, 256, 0, stream>>>(
        km8, (const u32*)qa, rowptr, csrc, mu + 4, (u32*)gagg, Na);

    // P6: out = gagg@w1T + xa@lwT + lin_b
    mfma_out<<<gba, 256, 0, stream>>>(gagg, w1T, xa, lwT, lin_b, out, Na);
}